// Round 4
// baseline (288.927 us; speedup 1.0000x reference)
//
#include <hip/hip_runtime.h>
#include <cstdint>
#include <cstddef>

// GRU B=16384 T=64 H=32, 3 bidir layers + FC(64->2) + tanh.
// R24: R23 + full-line h-stores in the split kernel. R23's counters showed
// WRITE_SIZE 16->132 MB/dispatch: the dual-wave uint2 (8B, stride-16) h-store
// pattern wrote hole-y partial 64B lines that streamed to HBM (~1.6 TB/s
// effective) and the store backpressure ate the occupancy win. Fix: after the
// per-step LDS h-exchange BOTH waves hold the full 8-unit f16 quad hv, so the
// designated wave (alternating by plane parity) stores it as one full uint4 —
// identical bytes/layout to R19's proven store pattern. Planes 0..63 each
// stored exactly once (wave0 even planes, wave1 odd). LAST kernel stays
// byte-for-byte R19. Keeps: wave-pair gate-tile split (4 waves/SIMD), f32x2
// packed gate math, direction-split (2,T,B,32) f16 buffers, f16 datapath,
// fp32 acc, 16 seqs/wave, permuted gate rows, exp2-folded weights, shared
// rcp, FC fused into L2 + fc_finish transpose.

#define BB 16384
#define TT 64
#define PS ((size_t)BB * 32)        // shorts per t-plane per direction
#define DS ((size_t)TT * PS)        // shorts per direction buffer
#define PT ((size_t)TT * BB * 2)    // floats per direction-partial buffer

typedef __attribute__((ext_vector_type(8))) _Float16 f16x8;
typedef __attribute__((ext_vector_type(4))) float f32x4;
typedef __attribute__((ext_vector_type(2))) float f32x2;

#if __has_builtin(__builtin_amdgcn_exp2f)
#define EXP2(x) __builtin_amdgcn_exp2f(x)
#else
#define EXP2(x) exp2f(x)
#endif
#if __has_builtin(__builtin_amdgcn_rcpf)
#define RCP(x) __builtin_amdgcn_rcpf(x)
#else
#define RCP(x) (1.0f / (x))
#endif

#define SR (-1.4426950408889634f)   // -log2(e)   for r,z gates
#define SN (-2.8853900817779268f)   // -2*log2(e) for n gate

__device__ __forceinline__ f32x2 mk2(float a, float b) {
    f32x2 v; v.x = a; v.y = b; return v;
}
__device__ __forceinline__ float tanh_fast(float x) { return 2.0f / (1.0f + __expf(-2.0f * x)) - 1.0f; }
__device__ __forceinline__ unsigned short f2h(float f) {
    _Float16 h = (_Float16)f;                      // RNE
    return __builtin_bit_cast(unsigned short, h);
}
__device__ __forceinline__ unsigned int cvt_pkh(float a, float b) {
#if __has_builtin(__builtin_amdgcn_cvt_pkrtz)
    typedef __fp16 h2_t __attribute__((ext_vector_type(2)));
    h2_t p = __builtin_amdgcn_cvt_pkrtz(a, b);
    return __builtin_bit_cast(unsigned int, p);
#else
    return (unsigned int)f2h(a) | ((unsigned int)f2h(b) << 16);
#endif
}
__device__ __forceinline__ f32x4 mfma16h(f16x8 a, f16x8 b, f32x4 c) {
    return __builtin_amdgcn_mfma_f32_16x16x32_f16(a, b, c, 0, 0, 0);
}

// Gates for a q-pair on packed f32 vectors (v_pk_* codegen).
// Inputs are exp2-prescaled preactivations (bias carried in MFMA C operand).
// sigma(x) = rcp(1+exp2(SR*x)); tanh(v) = 2*rcp(1+exp2(SN*v)) - 1.
__device__ __forceinline__ void gate_pair2(f32x2 aR, f32x2 aZ, f32x2 xN, f32x2 hN,
                                           f32x2& hp) {
    f32x2 er = mk2(EXP2(aR.x), EXP2(aR.y));
    f32x2 ez = mk2(EXP2(aZ.x), EXP2(aZ.y));
    f32x2 Ar = er + 1.f;
    f32x2 Az = ez + 1.f;
    float iR = RCP(Ar.x * Ar.y);
    float iZ = RCP(Az.x * Az.y);
    f32x2 r = mk2(iR * Ar.y, iR * Ar.x);
    f32x2 z = mk2(iZ * Az.y, iZ * Az.x);
    f32x2 v = r * hN + xN;                         // pk_fma
    f32x2 en = mk2(EXP2(v.x), EXP2(v.y));
    f32x2 An = en + 1.f;
    float iN = RCP(An.x * An.y);
    f32x2 n = mk2(fmaf(2.f, iN * An.y, -1.f), fmaf(2.f, iN * An.x, -1.f));
    hp = z * (hp - n) + n;                         // pk_sub / pk_fma
}

// A: lane = A[m=lane&15][k=(lane>>4)*8+j]   B: lane = B[k=(lane>>4)*8+j][n=lane&15]
// D: lane = D[row=(lane>>4)*4+reg][col=lane&15]

// ============================================================================
// gru_split: wave-pair gate-tile split (L0/L1 only). Wave w owns gate T-tile
// w: lane(qd,col) computes h units 8qd+4w+q for seq b0+col. B-frag for REC
// needs units 8qd+0..7 => own f16 quad + other wave's SAME-LANE quad via LDS.
// h-store: after the exchange both waves hold the full quad hv; wave (plane&1)
// stores it as one uint4 (full 64B lines per 4 lanes, R19 pattern).
// ============================================================================
template<bool IS_L0>
__global__ __launch_bounds__(128, 4)
void gru_split(const float* __restrict__ x0,
               const unsigned short* __restrict__ bin,     // f16 bits (2,T,B,32)
               const float* __restrict__ Wih,              // (2,96,I)
               const float* __restrict__ Whh,              // (2,96,32)
               const float* __restrict__ bih,              // (2,96)
               const float* __restrict__ bhh,              // (2,96)
               unsigned short* __restrict__ bout)          // f16 bits (2,T,B,32)
{
    __shared__ uint2 xch[2][2][64];     // [parity][wave][lane] f16 h-quad

    const int tid  = threadIdx.x;
    const int lane = tid & 63;
    const int w    = tid >> 6;           // wave index = gate T-tile
    const int g    = blockIdx.x;         // 0..2047
    const int d    = g >> 10;
    const int b0   = (g & 1023) * 16;    // 16 seqs per block
    const int col  = lane & 15;
    const int qd   = lane >> 4;

    // ---- Whh A-frags (tiles r,z,n with T=w), permuted rows, exp2-prescaled ----
    f16x8 whhF[3];
    {
        const float* wsrc = Whh + d * 96 * 32;
        #pragma unroll
        for (int gg = 0; gg < 3; ++gg) {
            const float sc = (gg < 2) ? SR : SN;
            const int row = gg * 32 + 8 * (col >> 2) + 4 * w + (col & 3);
            const float* pr = wsrc + row * 32 + qd * 8;
            unsigned short wbits[8];
            #pragma unroll
            for (int j = 0; j < 8; ++j) wbits[j] = f2h(pr[j] * sc);
            whhF[gg] = __builtin_bit_cast(f16x8, *(uint4*)wbits);
        }
    }

    // ---- Wih A-frags (T=w) or L0 scalar weights ----
    f16x8 wihF[3][2];
    float w0c[3][4], w1c[3][4];
    if constexpr (!IS_L0) {
        const float* wsrc = Wih + d * 96 * 64;
        #pragma unroll
        for (int gg = 0; gg < 3; ++gg) {
            const float sc = (gg < 2) ? SR : SN;
            const int row = gg * 32 + 8 * (col >> 2) + 4 * w + (col & 3);
            #pragma unroll
            for (int kc = 0; kc < 2; ++kc) {
                const float* pr = wsrc + row * 64 + kc * 32 + qd * 8;
                unsigned short wbits[8];
                #pragma unroll
                for (int j = 0; j < 8; ++j) wbits[j] = f2h(pr[j] * sc);
                wihF[gg][kc] = __builtin_bit_cast(f16x8, *(uint4*)wbits);
            }
        }
    } else {
        #pragma unroll
        for (int gg = 0; gg < 3; ++gg) {
            const float sc = (gg < 2) ? SR : SN;
            #pragma unroll
            for (int q = 0; q < 4; ++q) {
                const int row = gg * 32 + 8 * qd + 4 * w + q;
                const float* pr = Wih + d * 96 * 2 + row * 2;
                w0c[gg][q] = pr[0] * sc;
                w1c[gg][q] = pr[1] * sc;
            }
        }
    }

    // ---- biases as C-operand frags (prescaled), T=w slice ----
    f32x4 biasIn[3], biasHN;
    {
        const float* bi = bih + d * 96;
        const float* bh = bhh + d * 96;
        #pragma unroll
        for (int gg = 0; gg < 2; ++gg) {
            const int off = gg * 32 + 8 * qd + 4 * w;
            float4 a = *(const float4*)(bi + off);
            float4 b = *(const float4*)(bh + off);
            biasIn[gg][0] = (a.x + b.x) * SR; biasIn[gg][1] = (a.y + b.y) * SR;
            biasIn[gg][2] = (a.z + b.z) * SR; biasIn[gg][3] = (a.w + b.w) * SR;
        }
        const int off = 64 + 8 * qd + 4 * w;
        float4 a = *(const float4*)(bi + off);
        float4 b = *(const float4*)(bh + off);
        biasIn[2][0] = a.x * SN; biasIn[2][1] = a.y * SN;
        biasIn[2][2] = a.z * SN; biasIn[2][3] = a.w * SN;
        biasHN[0] = b.x * SN; biasHN[1] = b.y * SN;
        biasHN[2] = b.z * SN; biasHN[3] = b.w * SN;
    }

    const int t0 = d ? (TT - 1) : 0;
    const int dt = d ? -1 : 1;
    const ptrdiff_t dplane = (ptrdiff_t)dt * (ptrdiff_t)PS;

    f16x8 hF = {};
    float hprev[4] = {0.f, 0.f, 0.f, 0.f};
    uint2 hwOwn = {0u, 0u};
    f32x4 accA[3], accB[3], accHN;

    auto REC = [&](f32x4 (&acc)[3]) {
        acc[0] = mfma16h(whhF[0], hF, acc[0]);
        acc[1] = mfma16h(whhF[1], hF, acc[1]);
        accHN  = mfma16h(whhF[2], hF, biasHN);
    };

    auto PROJ = [&](f32x4 (&acc)[3], uint4 nx0, uint4 nx1, float2 nxs) {
        if constexpr (!IS_L0) {
            f16x8 a0 = __builtin_bit_cast(f16x8, nx0);   // k 0..31  = fwd units
            f16x8 a1 = __builtin_bit_cast(f16x8, nx1);   // k 32..63 = bwd units
            #pragma unroll
            for (int gg = 0; gg < 3; ++gg) {
                acc[gg] = mfma16h(wihF[gg][0], a0, biasIn[gg]);
                acc[gg] = mfma16h(wihF[gg][1], a1, acc[gg]);
            }
        } else {
            #pragma unroll
            for (int gg = 0; gg < 3; ++gg)
                #pragma unroll
                for (int q = 0; q < 4; ++q)
                    acc[gg][q] = fmaf(nxs.x, w0c[gg][q], fmaf(nxs.y, w1c[gg][q], biasIn[gg][q]));
        }
    };

    auto GATES = [&](f32x4 (&acc)[3]) {
        f32x2 hp01 = mk2(hprev[0], hprev[1]);
        f32x2 hp23 = mk2(hprev[2], hprev[3]);
        gate_pair2(mk2(acc[0][0], acc[0][1]), mk2(acc[1][0], acc[1][1]),
                   mk2(acc[2][0], acc[2][1]), mk2(accHN[0], accHN[1]), hp01);
        gate_pair2(mk2(acc[0][2], acc[0][3]), mk2(acc[1][2], acc[1][3]),
                   mk2(acc[2][2], acc[2][3]), mk2(accHN[2], accHN[3]), hp23);
        hprev[0] = hp01.x; hprev[1] = hp01.y;
        hprev[2] = hp23.x; hprev[3] = hp23.y;
        hwOwn.x = cvt_pkh(hp01.x, hp01.y);
        hwOwn.y = cvt_pkh(hp23.x, hp23.y);
    };

    // ---- pointers ----
    const unsigned short* pF = nullptr; const unsigned short* pB = nullptr;
    const float* pfx = nullptr;
    // full-quad store pointer: wave w stores planes w, w+2, w+4, ... (logical)
    unsigned short* sptr = bout + (size_t)d * DS + (size_t)t0 * PS
                         + (size_t)(b0 + col) * 32 + qd * 8
                         + (ptrdiff_t)w * dplane;

    // ---- prologue: step 0 (h=0, REC contributes only biasHN); no store yet ----
    if constexpr (!IS_L0) {
        const unsigned short* laneF = bin + (size_t)t0 * PS + (size_t)(b0 + col) * 32 + qd * 8;
        const unsigned short* laneB = laneF + DS;
        uint4 a = *(const uint4*)laneF, b = *(const uint4*)laneB;       // plane 0
        PROJ(accA, a, b, {});
        a = *(const uint4*)(laneF + dplane); b = *(const uint4*)(laneB + dplane); // plane 1
        accHN = biasHN;
        GATES(accA);                                   // h(0)
        xch[0][w][lane] = hwOwn;
        PROJ(accB, a, b, {});
        pF = laneF + 2 * dplane; pB = laneB + 2 * dplane;               // plane 2
    } else {
        const float* lane0 = x0 + ((size_t)(b0 + col) * TT + t0) * 2;
        float2 xs0 = *(const float2*)lane0;                             // plane 0
        float2 xs1 = *(const float2*)(lane0 + dt * 2);                  // plane 1
        PROJ(accA, {}, {}, xs0);
        accHN = biasHN;
        GATES(accA);                                   // h(0)
        xch[0][w][lane] = hwOwn;
        PROJ(accB, {}, {}, xs1);
        pfx = lane0 + dt * 4;                                           // plane 2
    }

    // One step s: barrier, read other h(s-1), form full hv, store h(s-1) by
    // wave (s-1)&1, REC, GATES(h(s)), write h(s) to slot[s&1], PROJ(x(s+1)).
    auto STEP = [&](f32x4 (&accCur)[3], f32x4 (&accNext)[3], int pCons) {
        __syncthreads();
        uint4 xn0 = {}, xn1 = {}; float2 xns = {};
        if constexpr (!IS_L0) {
            xn0 = *(const uint4*)pF; xn1 = *(const uint4*)pB;           // plane s+1
            pF += dplane; pB += dplane;
        } else {
            xns = *(const float2*)pfx; pfx += dt * 2;
        }
        uint2 oth = xch[pCons][1 - w][lane];
        uint4 hv;
        if (w == 0) { hv.x = hwOwn.x; hv.y = hwOwn.y; hv.z = oth.x; hv.w = oth.y; }
        else        { hv.x = oth.x;   hv.y = oth.y;   hv.z = hwOwn.x; hv.w = hwOwn.y; }
        hF = __builtin_bit_cast(f16x8, hv);
        if (w == pCons) {                   // plane s-1 has parity pCons
            *(uint4*)sptr = hv;
            sptr += 2 * dplane;
        }
        REC(accCur);
        GATES(accCur);
        xch[1 - pCons][w][lane] = hwOwn;
        PROJ(accNext, xn0, xn1, xns);
    };

    for (int k = 0; k < 31; ++k) {        // steps 1..62
        STEP(accB, accA, 0);              // step 2k+1, loads plane 2k+2
        STEP(accA, accB, 1);              // step 2k+2, loads plane 2k+3
    }

    // ---- step 63 (no x load, no PROJ); stores h(62) and h(63) ----
    __syncthreads();
    {
        uint2 oth = xch[0][1 - w][lane];
        uint4 hv;
        if (w == 0) { hv.x = hwOwn.x; hv.y = hwOwn.y; hv.z = oth.x; hv.w = oth.y; }
        else        { hv.x = oth.x;   hv.y = oth.y;   hv.z = hwOwn.x; hv.w = hwOwn.y; }
        hF = __builtin_bit_cast(f16x8, hv);
        if (w == 0) { *(uint4*)sptr = hv; sptr += 2 * dplane; }         // plane 62
        REC(accB);
        GATES(accB);                                   // h(63)
        xch[1][w][lane] = hwOwn;
        __syncthreads();
        if (w == 1) {
            uint2 oth2 = xch[1][0][lane];
            uint4 hv2;
            hv2.x = oth2.x; hv2.y = oth2.y; hv2.z = hwOwn.x; hv2.w = hwOwn.y;
            *(uint4*)sptr = hv2;                                        // plane 63
        }
    }
}

// ============================================================================
// gru_mfma: R19 original (verbatim), used for the LAST layer only.
// Gate-row permutation: block row position (T*16 + qd*4 + q) <- original unit
// 8qd+4T+q.
// ============================================================================
template<bool IS_L0, bool IS_LAST>
__global__ __launch_bounds__(256, 2)
void gru_mfma(const float* __restrict__ x0,
              const unsigned short* __restrict__ bin,      // f16 bits (2,T,B,32)
              const float* __restrict__ Wih,               // (2,96,I)
              const float* __restrict__ Whh,               // (2,96,32)
              const float* __restrict__ bih,               // (2,96)
              const float* __restrict__ bhh,               // (2,96)
              unsigned short* __restrict__ bout,           // f16 bits (2,T,B,32)
              const float* __restrict__ Wfc,               // (2,64)  [LAST]
              float* __restrict__ pbase)                   // (2,T,B,2) fp32 [LAST]
{
    const int tid  = threadIdx.x;
    const int lane = tid & 63;
    const int wv   = tid >> 6;
    const int g    = blockIdx.x * 4 + wv;        // 0..2047
    const int d    = g >> 10;
    const int b0   = (g & 1023) * 16;            // 16 seqs per wave
    const int col  = lane & 15;
    const int qd   = lane >> 4;

    // ---- Whh A-frags (single f16), permuted rows, exp2-prescaled ----
    f16x8 whhF[6];
    {
        const float* wsrc = Whh + d * 96 * 32;
        #pragma unroll
        for (int t = 0; t < 6; ++t) {
            const float sc = (t < 4) ? SR : SN;
            const int row = (t >> 1) * 32 + 8 * (col >> 2) + 4 * (t & 1) + (col & 3);
            const float* pr = wsrc + row * 32 + qd * 8;
            unsigned short wbits[8];
            #pragma unroll
            for (int j = 0; j < 8; ++j) wbits[j] = f2h(pr[j] * sc);
            whhF[t] = __builtin_bit_cast(f16x8, *(uint4*)wbits);
        }
    }

    // ---- Wih A-frags (single f16, permuted, prescaled) or L0 scalar weights ----
    f16x8 wihF[6][2];
    float w0c[6][4], w1c[6][4];
    if constexpr (!IS_L0) {
        const float* wsrc = Wih + d * 96 * 64;
        #pragma unroll
        for (int t = 0; t < 6; ++t) {
            const float sc = (t < 4) ? SR : SN;
            const int row = (t >> 1) * 32 + 8 * (col >> 2) + 4 * (t & 1) + (col & 3);
            #pragma unroll
            for (int kc = 0; kc < 2; ++kc) {
                const float* pr = wsrc + row * 64 + kc * 32 + qd * 8;
                unsigned short wbits[8];
                #pragma unroll
                for (int j = 0; j < 8; ++j) wbits[j] = f2h(pr[j] * sc);
                wihF[t][kc] = __builtin_bit_cast(f16x8, *(uint4*)wbits);
            }
        }
    } else {
        #pragma unroll
        for (int t = 0; t < 6; ++t) {
            const float sc = (t < 4) ? SR : SN;
            #pragma unroll
            for (int q = 0; q < 4; ++q) {
                const int row = (t >> 1) * 32 + 8 * qd + 4 * (t & 1) + q;
                const float* pr = Wih + d * 96 * 2 + row * 2;
                w0c[t][q] = pr[0] * sc;
                w1c[t][q] = pr[1] * sc;
            }
        }
    }

    // ---- biases as C-operand frags (prescaled) ----
    f32x4 biasIn[6], biasHN[2];
    {
        const float* bi = bih + d * 96;
        const float* bh = bhh + d * 96;
        #pragma unroll
        for (int t = 0; t < 4; ++t) {
            const int off = (t >> 1) * 32 + 8 * qd + 4 * (t & 1);
            float4 a = *(const float4*)(bi + off);
            float4 b = *(const float4*)(bh + off);
            biasIn[t][0] = (a.x + b.x) * SR; biasIn[t][1] = (a.y + b.y) * SR;
            biasIn[t][2] = (a.z + b.z) * SR; biasIn[t][3] = (a.w + b.w) * SR;
        }
        #pragma unroll
        for (int T = 0; T < 2; ++T) {
            const int off = 64 + 8 * qd + 4 * T;
            float4 a = *(const float4*)(bi + off);
            float4 b = *(const float4*)(bh + off);
            biasIn[4 + T][0] = a.x * SN; biasIn[4 + T][1] = a.y * SN;
            biasIn[4 + T][2] = a.z * SN; biasIn[4 + T][3] = a.w * SN;
            biasHN[T][0] = b.x * SN; biasHN[T][1] = b.y * SN;
            biasHN[T][2] = b.z * SN; biasHN[T][3] = b.w * SN;
        }
    }

    // ---- FC weights per lane (LAST): unit u = 8*qd + 4*T + q ----
    float wf0[2][4], wf1[2][4];
    if constexpr (IS_LAST) {
        #pragma unroll
        for (int T = 0; T < 2; ++T)
            #pragma unroll
            for (int q = 0; q < 4; ++q) {
                const int u = 8 * qd + 4 * T + q;
                wf0[T][q] = Wfc[d * 32 + u];
                wf1[T][q] = Wfc[64 + d * 32 + u];
            }
    }

    const int t0 = d ? (TT - 1) : 0;
    const int dt = d ? -1 : 1;
    const ptrdiff_t dplane = (ptrdiff_t)dt * (ptrdiff_t)PS;   // one t-plane step

    f16x8 hF = {};
    float hprev[2][4] = {{0.f,0.f,0.f,0.f},{0.f,0.f,0.f,0.f}};

    auto REC = [&](f32x4 (&acc)[6], f32x4 (&accHN)[2]) {
        #pragma unroll
        for (int t = 0; t < 4; ++t)
            acc[t] = mfma16h(whhF[t], hF, acc[t]);
        #pragma unroll
        for (int T = 0; T < 2; ++T)
            accHN[T] = mfma16h(whhF[4 + T], hF, biasHN[T]);
    };

    auto PROJ = [&](f32x4 (&accN)[6], uint4 nx0, uint4 nx1, float2 nxs) {
        if constexpr (!IS_L0) {
            f16x8 a0 = __builtin_bit_cast(f16x8, nx0);   // k 0..31  = fwd units
            f16x8 a1 = __builtin_bit_cast(f16x8, nx1);   // k 32..63 = bwd units
            #pragma unroll
            for (int t = 0; t < 6; ++t) {
                accN[t] = mfma16h(wihF[t][0], a0, biasIn[t]);
                accN[t] = mfma16h(wihF[t][1], a1, accN[t]);
            }
        } else {
            #pragma unroll
            for (int t = 0; t < 6; ++t)
                #pragma unroll
                for (int q = 0; q < 4; ++q)
                    accN[t][q] = fmaf(nxs.x, w0c[t][q], fmaf(nxs.y, w1c[t][q], biasIn[t][q]));
        }
    };

    // ---- gates (packed f32 math); delayed h-store (L0/L1) or FC partial (LAST) ----
    auto GATES = [&](f32x4 (&acc)[6], f32x4 (&accHN)[2], unsigned short* outp,
                     uint4& hwP, unsigned short*& opP, float* poutp) {
        unsigned int hw[4];
        #pragma unroll
        for (int T = 0; T < 2; ++T) {
            f32x2 hp01 = mk2(hprev[T][0], hprev[T][1]);
            f32x2 hp23 = mk2(hprev[T][2], hprev[T][3]);
            gate_pair2(mk2(acc[T][0], acc[T][1]), mk2(acc[2 + T][0], acc[2 + T][1]),
                       mk2(acc[4 + T][0], acc[4 + T][1]), mk2(accHN[T][0], accHN[T][1]), hp01);
            gate_pair2(mk2(acc[T][2], acc[T][3]), mk2(acc[2 + T][2], acc[2 + T][3]),
                       mk2(acc[4 + T][2], acc[4 + T][3]), mk2(accHN[T][2], accHN[T][3]), hp23);
            hprev[T][0] = hp01.x; hprev[T][1] = hp01.y;
            hprev[T][2] = hp23.x; hprev[T][3] = hp23.y;
            hw[2 * T]     = cvt_pkh(hp01.x, hp01.y);
            hw[2 * T + 1] = cvt_pkh(hp23.x, hp23.y);
        }
        hF = __builtin_bit_cast(f16x8, *(uint4*)hw);
        if constexpr (IS_LAST) {
            float p0 = 0.f, p1 = 0.f;
            #pragma unroll
            for (int T = 0; T < 2; ++T)
                #pragma unroll
                for (int q = 0; q < 4; ++q) {
                    p0 = fmaf(hprev[T][q], wf0[T][q], p0);
                    p1 = fmaf(hprev[T][q], wf1[T][q], p1);
                }
            p0 += __shfl_xor(p0, 16); p0 += __shfl_xor(p0, 32);
            p1 += __shfl_xor(p1, 16); p1 += __shfl_xor(p1, 32);
            if (qd == 0) *(float2*)poutp = make_float2(p0, p1);
        } else {
            *(uint4*)opP = hwP;                 // store the 2-steps-old value
            hwP = *(uint4*)hw;                  // bank this step's value
            opP = outp;
        }
    };

    // ---- x streams: even loads x[2k+2], odd loads x[2k+3]; F/B buffer pair ----
    f32x4 accA[6], accB[6], accHN[2];
    uint4 xc0 = {}, xc1 = {}, xe0 = {}, xe1 = {};
    float2 xsc = {}, xse = {};
    const unsigned short* xFE = nullptr; const unsigned short* xBE = nullptr;
    const unsigned short* xFO = nullptr; const unsigned short* xBO = nullptr;
    const float* xfpE = nullptr; const float* xfpO = nullptr;

    if constexpr (!IS_L0) {
        const unsigned short* pF = bin + (size_t)t0 * PS + (size_t)(b0 + col) * 32 + qd * 8;
        const unsigned short* pB = pF + DS;
        uint4 a = *(const uint4*)pF, b = *(const uint4*)pB;
        PROJ(accA, a, b, {});                         // acc for step 0
        xc0 = *(const uint4*)(pF + dplane);           // x[1]
        xc1 = *(const uint4*)(pB + dplane);
        xFE = pF + 2 * dplane; xBE = pB + 2 * dplane; // x[2]
        xFO = pF + 3 * dplane; xBO = pB + 3 * dplane; // x[3]
    } else {
        const float* p0 = x0 + ((size_t)(b0 + col) * TT + t0) * 2;
        float2 xs0 = *(const float2*)p0;
        PROJ(accA, {}, {}, xs0);
        xsc = *(const float2*)(p0 + dt * 2);          // x[1]
        xfpE = p0 + dt * 4;                           // x[2]
        xfpO = p0 + dt * 6;                           // x[3]
    }

    unsigned short* optrA = nullptr; unsigned short* optrB = nullptr;
    float* poutA = nullptr; float* poutB = nullptr;
    const ptrdiff_t dpp = (ptrdiff_t)dt * (ptrdiff_t)BB * 2;
    if constexpr (IS_LAST) {
        poutA = pbase + (size_t)d * PT + ((size_t)t0 * BB + b0 + col) * 2;
        poutB = poutA + dpp;
    } else {
        optrA = bout + (size_t)d * DS + (size_t)t0 * PS + (size_t)(b0 + col) * 32 + qd * 8;
        optrB = optrA + dplane;
    }

    // delayed-store state (L0/L1): primed with zero-writes to step-0/1 addresses
    uint4 hwPrevA = {}, hwPrevB = {};
    unsigned short* opPrevA = optrA;
    unsigned short* opPrevB = optrB;

    for (int k = 0; k < 31; ++k) {                    // steps 0..61
        if constexpr (!IS_L0) {
            xe0 = *(const uint4*)xFE; xe1 = *(const uint4*)xBE;
            xFE += 2 * dplane; xBE += 2 * dplane;
        } else { xse = *(const float2*)xfpE; xfpE += dt * 4; }
        REC(accA, accHN);
        PROJ(accB, xc0, xc1, xsc);
        GATES(accA, accHN, optrA, hwPrevA, opPrevA, poutA);
        if constexpr (IS_LAST) poutA += 2 * dpp; else optrA += 2 * dplane;
        if constexpr (!IS_L0) {
            xc0 = *(const uint4*)xFO; xc1 = *(const uint4*)xBO;
            xFO += 2 * dplane; xBO += 2 * dplane;
        } else { xsc = *(const float2*)xfpO; xfpO += dt * 4; }
        REC(accB, accHN);
        PROJ(accA, xe0, xe1, xse);
        GATES(accB, accHN, optrB, hwPrevB, opPrevB, poutB);
        if constexpr (IS_LAST) poutB += 2 * dpp; else optrB += 2 * dplane;
    }
    REC(accA, accHN);                                 // step 62
    PROJ(accB, xc0, xc1, xsc);
    GATES(accA, accHN, optrA, hwPrevA, opPrevA, poutA);
    REC(accB, accHN);                                 // step 63
    GATES(accB, accHN, optrB, hwPrevB, opPrevB, poutB);
    if constexpr (!IS_LAST) {
        *(uint4*)opPrevA = hwPrevA;                   // flush banked values
        *(uint4*)opPrevB = hwPrevB;
    }
}

// out[b][t] = tanh(pf[t][b] + pb[t][b] + bfc), with an LDS 64x64 transpose
__global__ __launch_bounds__(256)
void fc_finish(const float* __restrict__ pf,    // (T,B,2)
               const float* __restrict__ pb,    // (T,B,2)
               const float* __restrict__ bfc,   // (2,)
               float* __restrict__ out)         // (B,T,2)
{
    __shared__ float2 tile[64][65];
    const int tid = threadIdx.x;
    const int bbase = blockIdx.x * 64;
    const float c0 = bfc[0], c1 = bfc[1];
    #pragma unroll
    for (int tp = 0; tp < 16; ++tp) {             // read coalesced over b
        const int t = tp * 4 + (tid >> 6);
        const int bl = tid & 63;
        const size_t idx = ((size_t)t * BB + bbase + bl) * 2;
        float2 vf = *(const float2*)(pf + idx);
        float2 vb = *(const float2*)(pb + idx);
        float2 o;
        o.x = tanh_fast(vf.x + vb.x + c0);
        o.y = tanh_fast(vf.y + vb.y + c1);
        tile[t][bl] = o;
    }
    __syncthreads();
    #pragma unroll
    for (int bp = 0; bp < 16; ++bp) {             // write coalesced over t
        const int bl = bp * 4 + (tid >> 6);
        const int t = tid & 63;
        *(float2*)(out + ((size_t)(bbase + bl) * TT + t) * 2) = tile[t][bl];
    }
}

extern "C" void kernel_launch(void* const* d_in, const int* in_sizes, int n_in,
                              void* d_out, int out_size, void* d_ws, size_t ws_size,
                              hipStream_t stream)
{
    const float* x    = (const float*)d_in[0];
    const float* Wih0 = (const float*)d_in[1];
    const float* Whh0 = (const float*)d_in[2];
    const float* bih0 = (const float*)d_in[3];
    const float* bhh0 = (const float*)d_in[4];
    const float* WihL = (const float*)d_in[5];
    const float* WhhL = (const float*)d_in[6];
    const float* bihL = (const float*)d_in[7];
    const float* bhhL = (const float*)d_in[8];
    const float* Wfc  = (const float*)d_in[9];
    const float* bfc  = (const float*)d_in[10];

    unsigned short* buf0 = (unsigned short*)d_ws;           // (2,T,B,32) f16
    unsigned short* buf1 = buf0 + 2 * DS;                   // (2,T,B,32) f16
    float* pbase = (float*)d_ws;                            // (2,T,B,2) fp32, reuses buf0
    float* out = (float*)d_out;

    gru_split<true><<<2048, 128, 0, stream>>>(
        x, nullptr, Wih0, Whh0, bih0, bhh0, buf0);
    gru_split<false><<<2048, 128, 0, stream>>>(
        nullptr, buf0, WihL, WhhL, bihL, bhhL, buf1);
    gru_mfma<false, true><<<512, 256, 0, stream>>>(
        nullptr, buf1, WihL + 2 * 96 * 64, WhhL + 2 * 96 * 32,
        bihL + 2 * 96, bhhL + 2 * 96, nullptr, Wfc, pbase);
    fc_finish<<<BB / 64, 256, 0, stream>>>(
        pbase, pbase + PT, bfc, out);
}

// Round 7
// 265.637 us; speedup vs baseline: 1.0877x; 1.0877x over previous
//
#include <hip/hip_runtime.h>
#include <cstdint>
#include <cstddef>

// GRU B=16384 T=64 H=32, 3 bidir layers + FC(64->2) + tanh.
// R27 = R19 verbatim resubmit (R26 bench was an infra failure: "MI355X
// container failed twice" -- no kernel signal). Proven best: 267-270us,
// absmax 0.0039. Session post-mortem R20-R25: occupancy levers (wave-pair
// split 4 waves/SIMD, R23/24) and ILP levers (dual-chain, R25) both
// null-or-broken -- per-SIMD wall is ~2960cy/step regardless of wave
// arrangement (serial trans->hF->MFMA chain, ~52% issue efficiency), and
// structural rewrites of the gate path re-round the f16 trajectory past the
// 5-ulp threshold (R22 0.031, R25 0.046).
// Keeps: f32x2 packed gate math (v_pk_*_f32), direction-split (2,T,B,32) f16
// buffers (no store-RFO), f16 datapath, fp32 acc, 16 seqs/wave, permuted gate
// rows (D-frag==B-frag), zero-LDS recurrence, exp2-folded weights, shared
// rcp, delayed h-stores, FC fused into L2 + fc_finish transpose.

#define BB 16384
#define TT 64
#define PS ((size_t)BB * 32)        // shorts per t-plane per direction
#define DS ((size_t)TT * PS)        // shorts per direction buffer
#define PT ((size_t)TT * BB * 2)    // floats per direction-partial buffer

typedef __attribute__((ext_vector_type(8))) _Float16 f16x8;
typedef __attribute__((ext_vector_type(4))) float f32x4;
typedef __attribute__((ext_vector_type(2))) float f32x2;

#if __has_builtin(__builtin_amdgcn_exp2f)
#define EXP2(x) __builtin_amdgcn_exp2f(x)
#else
#define EXP2(x) exp2f(x)
#endif
#if __has_builtin(__builtin_amdgcn_rcpf)
#define RCP(x) __builtin_amdgcn_rcpf(x)
#else
#define RCP(x) (1.0f / (x))
#endif

#define SR (-1.4426950408889634f)   // -log2(e)   for r,z gates
#define SN (-2.8853900817779268f)   // -2*log2(e) for n gate

__device__ __forceinline__ f32x2 mk2(float a, float b) {
    f32x2 v; v.x = a; v.y = b; return v;
}
__device__ __forceinline__ float tanh_fast(float x) { return 2.0f / (1.0f + __expf(-2.0f * x)) - 1.0f; }
__device__ __forceinline__ unsigned short f2h(float f) {
    _Float16 h = (_Float16)f;                      // RNE
    return __builtin_bit_cast(unsigned short, h);
}
__device__ __forceinline__ unsigned int cvt_pkh(float a, float b) {
#if __has_builtin(__builtin_amdgcn_cvt_pkrtz)
    typedef __fp16 h2_t __attribute__((ext_vector_type(2)));
    h2_t p = __builtin_amdgcn_cvt_pkrtz(a, b);
    return __builtin_bit_cast(unsigned int, p);
#else
    return (unsigned int)f2h(a) | ((unsigned int)f2h(b) << 16);
#endif
}
__device__ __forceinline__ f32x4 mfma16h(f16x8 a, f16x8 b, f32x4 c) {
    return __builtin_amdgcn_mfma_f32_16x16x32_f16(a, b, c, 0, 0, 0);
}

// Gates for a q-pair on packed f32 vectors (v_pk_* codegen).
// Inputs are exp2-prescaled preactivations (bias carried in MFMA C operand).
// sigma(x) = rcp(1+exp2(SR*x)); tanh(v) = 2*rcp(1+exp2(SN*v)) - 1.
__device__ __forceinline__ void gate_pair2(f32x2 aR, f32x2 aZ, f32x2 xN, f32x2 hN,
                                           f32x2& hp) {
    f32x2 er = mk2(EXP2(aR.x), EXP2(aR.y));
    f32x2 ez = mk2(EXP2(aZ.x), EXP2(aZ.y));
    f32x2 Ar = er + 1.f;
    f32x2 Az = ez + 1.f;
    float iR = RCP(Ar.x * Ar.y);
    float iZ = RCP(Az.x * Az.y);
    f32x2 r = mk2(iR * Ar.y, iR * Ar.x);
    f32x2 z = mk2(iZ * Az.y, iZ * Az.x);
    f32x2 v = r * hN + xN;                         // pk_fma
    f32x2 en = mk2(EXP2(v.x), EXP2(v.y));
    f32x2 An = en + 1.f;
    float iN = RCP(An.x * An.y);
    f32x2 n = mk2(fmaf(2.f, iN * An.y, -1.f), fmaf(2.f, iN * An.x, -1.f));
    hp = z * (hp - n) + n;                         // pk_sub / pk_fma
}

// A: lane = A[m=lane&15][k=(lane>>4)*8+j]   B: lane = B[k=(lane>>4)*8+j][n=lane&15]
// D: lane = D[row=(lane>>4)*4+reg][col=lane&15]
// Gate-row permutation: block row position (T*16 + qd*4 + q) <- original unit 8qd+4T+q.

template<bool IS_L0, bool IS_LAST>
__global__ __launch_bounds__(256, 2)
void gru_mfma(const float* __restrict__ x0,
              const unsigned short* __restrict__ bin,      // f16 bits (2,T,B,32)
              const float* __restrict__ Wih,               // (2,96,I)
              const float* __restrict__ Whh,               // (2,96,32)
              const float* __restrict__ bih,               // (2,96)
              const float* __restrict__ bhh,               // (2,96)
              unsigned short* __restrict__ bout,           // f16 bits (2,T,B,32)
              const float* __restrict__ Wfc,               // (2,64)  [LAST]
              float* __restrict__ pbase)                   // (2,T,B,2) fp32 [LAST]
{
    const int tid  = threadIdx.x;
    const int lane = tid & 63;
    const int wv   = tid >> 6;
    const int g    = blockIdx.x * 4 + wv;        // 0..2047
    const int d    = g >> 10;
    const int b0   = (g & 1023) * 16;            // 16 seqs per wave
    const int col  = lane & 15;
    const int qd   = lane >> 4;

    // ---- Whh A-frags (single f16), permuted rows, exp2-prescaled ----
    f16x8 whhF[6];
    {
        const float* wsrc = Whh + d * 96 * 32;
        #pragma unroll
        for (int t = 0; t < 6; ++t) {
            const float sc = (t < 4) ? SR : SN;
            const int row = (t >> 1) * 32 + 8 * (col >> 2) + 4 * (t & 1) + (col & 3);
            const float* pr = wsrc + row * 32 + qd * 8;
            unsigned short wbits[8];
            #pragma unroll
            for (int j = 0; j < 8; ++j) wbits[j] = f2h(pr[j] * sc);
            whhF[t] = __builtin_bit_cast(f16x8, *(uint4*)wbits);
        }
    }

    // ---- Wih A-frags (single f16, permuted, prescaled) or L0 scalar weights ----
    f16x8 wihF[6][2];
    float w0c[6][4], w1c[6][4];
    if constexpr (!IS_L0) {
        const float* wsrc = Wih + d * 96 * 64;
        #pragma unroll
        for (int t = 0; t < 6; ++t) {
            const float sc = (t < 4) ? SR : SN;
            const int row = (t >> 1) * 32 + 8 * (col >> 2) + 4 * (t & 1) + (col & 3);
            #pragma unroll
            for (int kc = 0; kc < 2; ++kc) {
                const float* pr = wsrc + row * 64 + kc * 32 + qd * 8;
                unsigned short wbits[8];
                #pragma unroll
                for (int j = 0; j < 8; ++j) wbits[j] = f2h(pr[j] * sc);
                wihF[t][kc] = __builtin_bit_cast(f16x8, *(uint4*)wbits);
            }
        }
    } else {
        #pragma unroll
        for (int t = 0; t < 6; ++t) {
            const float sc = (t < 4) ? SR : SN;
            #pragma unroll
            for (int q = 0; q < 4; ++q) {
                const int row = (t >> 1) * 32 + 8 * qd + 4 * (t & 1) + q;
                const float* pr = Wih + d * 96 * 2 + row * 2;
                w0c[t][q] = pr[0] * sc;
                w1c[t][q] = pr[1] * sc;
            }
        }
    }

    // ---- biases as C-operand frags (prescaled) ----
    f32x4 biasIn[6], biasHN[2];
    {
        const float* bi = bih + d * 96;
        const float* bh = bhh + d * 96;
        #pragma unroll
        for (int t = 0; t < 4; ++t) {
            const int off = (t >> 1) * 32 + 8 * qd + 4 * (t & 1);
            float4 a = *(const float4*)(bi + off);
            float4 b = *(const float4*)(bh + off);
            biasIn[t][0] = (a.x + b.x) * SR; biasIn[t][1] = (a.y + b.y) * SR;
            biasIn[t][2] = (a.z + b.z) * SR; biasIn[t][3] = (a.w + b.w) * SR;
        }
        #pragma unroll
        for (int T = 0; T < 2; ++T) {
            const int off = 64 + 8 * qd + 4 * T;
            float4 a = *(const float4*)(bi + off);
            float4 b = *(const float4*)(bh + off);
            biasIn[4 + T][0] = a.x * SN; biasIn[4 + T][1] = a.y * SN;
            biasIn[4 + T][2] = a.z * SN; biasIn[4 + T][3] = a.w * SN;
            biasHN[T][0] = b.x * SN; biasHN[T][1] = b.y * SN;
            biasHN[T][2] = b.z * SN; biasHN[T][3] = b.w * SN;
        }
    }

    // ---- FC weights per lane (LAST): unit u = 8*qd + 4*T + q ----
    float wf0[2][4], wf1[2][4];
    if constexpr (IS_LAST) {
        #pragma unroll
        for (int T = 0; T < 2; ++T)
            #pragma unroll
            for (int q = 0; q < 4; ++q) {
                const int u = 8 * qd + 4 * T + q;
                wf0[T][q] = Wfc[d * 32 + u];
                wf1[T][q] = Wfc[64 + d * 32 + u];
            }
    }

    const int t0 = d ? (TT - 1) : 0;
    const int dt = d ? -1 : 1;
    const ptrdiff_t dplane = (ptrdiff_t)dt * (ptrdiff_t)PS;   // one t-plane step

    f16x8 hF = {};
    float hprev[2][4] = {{0.f,0.f,0.f,0.f},{0.f,0.f,0.f,0.f}};

    auto REC = [&](f32x4 (&acc)[6], f32x4 (&accHN)[2]) {
        #pragma unroll
        for (int t = 0; t < 4; ++t)
            acc[t] = mfma16h(whhF[t], hF, acc[t]);
        #pragma unroll
        for (int T = 0; T < 2; ++T)
            accHN[T] = mfma16h(whhF[4 + T], hF, biasHN[T]);
    };

    auto PROJ = [&](f32x4 (&accN)[6], uint4 nx0, uint4 nx1, float2 nxs) {
        if constexpr (!IS_L0) {
            f16x8 a0 = __builtin_bit_cast(f16x8, nx0);   // k 0..31  = fwd units
            f16x8 a1 = __builtin_bit_cast(f16x8, nx1);   // k 32..63 = bwd units
            #pragma unroll
            for (int t = 0; t < 6; ++t) {
                accN[t] = mfma16h(wihF[t][0], a0, biasIn[t]);
                accN[t] = mfma16h(wihF[t][1], a1, accN[t]);
            }
        } else {
            #pragma unroll
            for (int t = 0; t < 6; ++t)
                #pragma unroll
                for (int q = 0; q < 4; ++q)
                    accN[t][q] = fmaf(nxs.x, w0c[t][q], fmaf(nxs.y, w1c[t][q], biasIn[t][q]));
        }
    };

    // ---- gates (packed f32 math); delayed h-store (L0/L1) or FC partial (LAST) ----
    auto GATES = [&](f32x4 (&acc)[6], f32x4 (&accHN)[2], unsigned short* outp,
                     uint4& hwP, unsigned short*& opP, float* poutp) {
        unsigned int hw[4];
        #pragma unroll
        for (int T = 0; T < 2; ++T) {
            f32x2 hp01 = mk2(hprev[T][0], hprev[T][1]);
            f32x2 hp23 = mk2(hprev[T][2], hprev[T][3]);
            gate_pair2(mk2(acc[T][0], acc[T][1]), mk2(acc[2 + T][0], acc[2 + T][1]),
                       mk2(acc[4 + T][0], acc[4 + T][1]), mk2(accHN[T][0], accHN[T][1]), hp01);
            gate_pair2(mk2(acc[T][2], acc[T][3]), mk2(acc[2 + T][2], acc[2 + T][3]),
                       mk2(acc[4 + T][2], acc[4 + T][3]), mk2(accHN[T][2], accHN[T][3]), hp23);
            hprev[T][0] = hp01.x; hprev[T][1] = hp01.y;
            hprev[T][2] = hp23.x; hprev[T][3] = hp23.y;
            hw[2 * T]     = cvt_pkh(hp01.x, hp01.y);
            hw[2 * T + 1] = cvt_pkh(hp23.x, hp23.y);
        }
        hF = __builtin_bit_cast(f16x8, *(uint4*)hw);
        if constexpr (IS_LAST) {
            float p0 = 0.f, p1 = 0.f;
            #pragma unroll
            for (int T = 0; T < 2; ++T)
                #pragma unroll
                for (int q = 0; q < 4; ++q) {
                    p0 = fmaf(hprev[T][q], wf0[T][q], p0);
                    p1 = fmaf(hprev[T][q], wf1[T][q], p1);
                }
            p0 += __shfl_xor(p0, 16); p0 += __shfl_xor(p0, 32);
            p1 += __shfl_xor(p1, 16); p1 += __shfl_xor(p1, 32);
            if (qd == 0) *(float2*)poutp = make_float2(p0, p1);
        } else {
            *(uint4*)opP = hwP;                 // store the 2-steps-old value
            hwP = *(uint4*)hw;                  // bank this step's value
            opP = outp;
        }
    };

    // ---- x streams: even loads x[2k+2], odd loads x[2k+3]; F/B buffer pair ----
    f32x4 accA[6], accB[6], accHN[2];
    uint4 xc0 = {}, xc1 = {}, xe0 = {}, xe1 = {};
    float2 xsc = {}, xse = {};
    const unsigned short* xFE = nullptr; const unsigned short* xBE = nullptr;
    const unsigned short* xFO = nullptr; const unsigned short* xBO = nullptr;
    const float* xfpE = nullptr; const float* xfpO = nullptr;

    if constexpr (!IS_L0) {
        const unsigned short* pF = bin + (size_t)t0 * PS + (size_t)(b0 + col) * 32 + qd * 8;
        const unsigned short* pB = pF + DS;
        uint4 a = *(const uint4*)pF, b = *(const uint4*)pB;
        PROJ(accA, a, b, {});                         // acc for step 0
        xc0 = *(const uint4*)(pF + dplane);           // x[1]
        xc1 = *(const uint4*)(pB + dplane);
        xFE = pF + 2 * dplane; xBE = pB + 2 * dplane; // x[2]
        xFO = pF + 3 * dplane; xBO = pB + 3 * dplane; // x[3]
    } else {
        const float* p0 = x0 + ((size_t)(b0 + col) * TT + t0) * 2;
        float2 xs0 = *(const float2*)p0;
        PROJ(accA, {}, {}, xs0);
        xsc = *(const float2*)(p0 + dt * 2);          // x[1]
        xfpE = p0 + dt * 4;                           // x[2]
        xfpO = p0 + dt * 6;                           // x[3]
    }

    unsigned short* optrA = nullptr; unsigned short* optrB = nullptr;
    float* poutA = nullptr; float* poutB = nullptr;
    const ptrdiff_t dpp = (ptrdiff_t)dt * (ptrdiff_t)BB * 2;
    if constexpr (IS_LAST) {
        poutA = pbase + (size_t)d * PT + ((size_t)t0 * BB + b0 + col) * 2;
        poutB = poutA + dpp;
    } else {
        optrA = bout + (size_t)d * DS + (size_t)t0 * PS + (size_t)(b0 + col) * 32 + qd * 8;
        optrB = optrA + dplane;
    }

    // delayed-store state (L0/L1): primed with zero-writes to step-0/1 addresses
    uint4 hwPrevA = {}, hwPrevB = {};
    unsigned short* opPrevA = optrA;
    unsigned short* opPrevB = optrB;

    for (int k = 0; k < 31; ++k) {                    // steps 0..61
        if constexpr (!IS_L0) {
            xe0 = *(const uint4*)xFE; xe1 = *(const uint4*)xBE;
            xFE += 2 * dplane; xBE += 2 * dplane;
        } else { xse = *(const float2*)xfpE; xfpE += dt * 4; }
        REC(accA, accHN);
        PROJ(accB, xc0, xc1, xsc);
        GATES(accA, accHN, optrA, hwPrevA, opPrevA, poutA);
        if constexpr (IS_LAST) poutA += 2 * dpp; else optrA += 2 * dplane;
        if constexpr (!IS_L0) {
            xc0 = *(const uint4*)xFO; xc1 = *(const uint4*)xBO;
            xFO += 2 * dplane; xBO += 2 * dplane;
        } else { xsc = *(const float2*)xfpO; xfpO += dt * 4; }
        REC(accB, accHN);
        PROJ(accA, xe0, xe1, xse);
        GATES(accB, accHN, optrB, hwPrevB, opPrevB, poutB);
        if constexpr (IS_LAST) poutB += 2 * dpp; else optrB += 2 * dplane;
    }
    REC(accA, accHN);                                 // step 62
    PROJ(accB, xc0, xc1, xsc);
    GATES(accA, accHN, optrA, hwPrevA, opPrevA, poutA);
    REC(accB, accHN);                                 // step 63
    GATES(accB, accHN, optrB, hwPrevB, opPrevB, poutB);
    if constexpr (!IS_LAST) {
        *(uint4*)opPrevA = hwPrevA;                   // flush banked values
        *(uint4*)opPrevB = hwPrevB;
    }
}

// out[b][t] = tanh(pf[t][b] + pb[t][b] + bfc), with an LDS 64x64 transpose
__global__ __launch_bounds__(256)
void fc_finish(const float* __restrict__ pf,    // (T,B,2)
               const float* __restrict__ pb,    // (T,B,2)
               const float* __restrict__ bfc,   // (2,)
               float* __restrict__ out)         // (B,T,2)
{
    __shared__ float2 tile[64][65];
    const int tid = threadIdx.x;
    const int bbase = blockIdx.x * 64;
    const float c0 = bfc[0], c1 = bfc[1];
    #pragma unroll
    for (int tp = 0; tp < 16; ++tp) {             // read coalesced over b
        const int t = tp * 4 + (tid >> 6);
        const int bl = tid & 63;
        const size_t idx = ((size_t)t * BB + bbase + bl) * 2;
        float2 vf = *(const float2*)(pf + idx);
        float2 vb = *(const float2*)(pb + idx);
        float2 o;
        o.x = tanh_fast(vf.x + vb.x + c0);
        o.y = tanh_fast(vf.y + vb.y + c1);
        tile[t][bl] = o;
    }
    __syncthreads();
    #pragma unroll
    for (int bp = 0; bp < 16; ++bp) {             // write coalesced over t
        const int bl = bp * 4 + (tid >> 6);
        const int t = tid & 63;
        *(float2*)(out + ((size_t)(bbase + bl) * TT + t) * 2) = tile[t][bl];
    }
}

extern "C" void kernel_launch(void* const* d_in, const int* in_sizes, int n_in,
                              void* d_out, int out_size, void* d_ws, size_t ws_size,
                              hipStream_t stream)
{
    const float* x    = (const float*)d_in[0];
    const float* Wih0 = (const float*)d_in[1];
    const float* Whh0 = (const float*)d_in[2];
    const float* bih0 = (const float*)d_in[3];
    const float* bhh0 = (const float*)d_in[4];
    const float* WihL = (const float*)d_in[5];
    const float* WhhL = (const float*)d_in[6];
    const float* bihL = (const float*)d_in[7];
    const float* bhhL = (const float*)d_in[8];
    const float* Wfc  = (const float*)d_in[9];
    const float* bfc  = (const float*)d_in[10];

    unsigned short* buf0 = (unsigned short*)d_ws;           // (2,T,B,32) f16
    unsigned short* buf1 = buf0 + 2 * DS;                   // (2,T,B,32) f16
    float* pbase = (float*)d_ws;                            // (2,T,B,2) fp32, reuses buf0
    float* out = (float*)d_out;

    gru_mfma<true, false><<<512, 256, 0, stream>>>(
        x, nullptr, Wih0, Whh0, bih0, bhh0, buf0, nullptr, nullptr);
    gru_mfma<false, false><<<512, 256, 0, stream>>>(
        nullptr, buf0, WihL, WhhL, bihL, bhhL, buf1, nullptr, nullptr);
    gru_mfma<false, true><<<512, 256, 0, stream>>>(
        nullptr, buf1, WihL + 2 * 96 * 64, WhhL + 2 * 96 * 32,
        bihL + 2 * 96, bhhL + 2 * 96, nullptr, Wfc, pbase);
    fc_finish<<<BB / 64, 256, 0, stream>>>(
        pbase, pbase + PT, bfc, out);
}